// Round 1
// baseline (756.113 us; speedup 1.0000x reference)
//
#include <hip/hip_runtime.h>
#include <hip/hip_bf16.h>
#include <math.h>

// Problem constants (from reference): N=8, T=64, A=65536, C=80
#define NB 8
#define TB 64
#define AB 65536
#define CB 80
#define EPSF 1e-6f

// ---------------- workspace layout ----------------
// [0,8)        double cls_sum
// [8,16)       double box_sum
// [16,48)      int    pos_cnt[8]
// [64,4160)    u64    gt_key[N*T]   (packed best-anchor per GT)
// [4608, +2MB) float  max_iou[N*A]
// [next, +2MB) int    assigned[N*A]
#define WS_GTKEY_OFF   64
#define WS_MAXIOU_OFF  4608
#define WS_ASSIGN_OFF  (4608 + NB*AB*4)
#define WS_HDR_BYTES   4608   // region that must be zeroed each launch

// ---------------- kernel A: anchor<->gt assignment ----------------
// grid: N*A/256 blocks of 256 threads; block = 256 consecutive anchors of one batch i
__global__ __launch_bounds__(256) void assign_kernel(
    const float* __restrict__ bbox_true,   // (N,T,4)
    const float* __restrict__ anchors,     // (A,4)
    float* __restrict__ max_iou,           // (N,A)
    int*   __restrict__ assigned,          // (N,A)
    unsigned long long* __restrict__ gt_key) // (N,T)
{
    __shared__ float4 s_box[TB];
    __shared__ float  s_a1[TB];   // gt area, or -1 if invalid
    __shared__ unsigned long long s_key[TB];

    const int blk  = blockIdx.x;
    const int i    = blk >> 8;            // A/256 = 256 blocks per batch
    const int abase = (blk & 255) << 8;
    const int tid  = threadIdx.x;

    if (tid < TB) {
        float4 b = ((const float4*)bbox_true)[i * TB + tid];
        bool valid = (b.x > 0.f) || (b.y > 0.f) || (b.z > 0.f) || (b.w > 0.f);
        float a1 = fmaxf(b.z - b.x, 0.f) * fmaxf(b.w - b.y, 0.f);
        s_box[tid] = b;
        s_a1[tid]  = valid ? a1 : -1.0f;
        s_key[tid] = 0ull;
    }
    __syncthreads();

    const int a = abase + tid;
    const float4 an = ((const float4*)anchors)[a];
    const float a2 = fmaxf(an.z - an.x, 0.f) * fmaxf(an.w - an.y, 0.f);

    float best = -1.0f;
    int bestt = 0;
    #pragma unroll 8
    for (int t = 0; t < TB; ++t) {
        float a1 = s_a1[t];
        float iou = -1.0f;
        if (a1 >= 0.f) {
            float4 b = s_box[t];
            float lx = fmaxf(b.x, an.x), ly = fmaxf(b.y, an.y);
            float rx = fminf(b.z, an.z), ry = fminf(b.w, an.w);
            float w = fmaxf(rx - lx, 0.f), h = fmaxf(ry - ly, 0.f);
            float inter = w * h;
            float uni = a1 + a2 - inter;
            iou = inter / fmaxf(uni, 1e-10f);
            if (iou > 0.f) {
                // higher iou wins; tie -> smaller anchor index (matches jnp.argmax)
                unsigned long long key =
                    ((unsigned long long)__float_as_uint(iou) << 32) |
                    (unsigned long long)((unsigned)a ^ 0xFFFFFFFFu);
                if (key > s_key[t])  // racy hint read; atomic below is authoritative
                    atomicMax(&s_key[t], key);
            }
        }
        if (iou > best) { best = iou; bestt = t; }  // strict > => first-index wins
    }
    max_iou[i * AB + a]  = best;
    assigned[i * AB + a] = bestt;

    __syncthreads();
    if (tid < TB) {
        unsigned long long k = s_key[tid];
        if (k) atomicMax(&gt_key[i * TB + tid], k);
    }
}

// ---------------- kernel B: low-quality match override ----------------
// sequential per batch => deterministic last-gt-wins (numpy fancy-assign semantics)
__global__ void lq_kernel(const unsigned long long* __restrict__ gt_key,
                          float* __restrict__ max_iou,
                          int*   __restrict__ assigned)
{
    int i = threadIdx.x;
    if (i < NB) {
        for (int t = 0; t < TB; ++t) {
            unsigned long long k = gt_key[i * TB + t];
            if (k) {  // nonzero iff gt t valid and gt_best_iou > 0
                int a = (int)((unsigned)(k & 0xFFFFFFFFull) ^ 0xFFFFFFFFu);
                assigned[i * AB + a] = t;
                max_iou[i * AB + a]  = 2.0f;  // force positive
            }
        }
    }
}

// ---------------- focal / smooth-l1 helpers ----------------
__device__ __forceinline__ float focal_bce(float y, float l) {
    float ce = fmaxf(l, 0.f) - l * y + log1pf(expf(-fabsf(l)));
    float p  = 1.f / (1.f + expf(-l));
    float pt = y * p + (1.f - y) * (1.f - p);
    float at = y * 0.25f + (1.f - y) * 0.75f;
    float om = 1.f - pt;
    return at * om * om * ce;
}
__device__ __forceinline__ float smooth_l1(float x) {
    float d = fabsf(x);
    return d < (1.f / 9.f) ? 4.5f * d * d : d - (0.5f / 9.f);
}

// ---------------- kernel C: loss accumulation ----------------
// 320 threads = 16 anchors x 20 float4-chunks of the 80 classes.
// grid: N*A/16 blocks (one batch per block since A%16==0, 4096 blocks per i)
__global__ __launch_bounds__(320) void loss_kernel(
    const float* __restrict__ y_true,     // (N,T,C)
    const float* __restrict__ bbox_true,  // (N,T,4)
    const float* __restrict__ y_pred,     // (N,A,C)
    const float* __restrict__ bbox_pred,  // (N,A,4)
    const float* __restrict__ anchors,    // (A,4)
    const float* __restrict__ max_iou,    // (N,A)
    const int*   __restrict__ assigned,   // (N,A)
    double* __restrict__ cls_sum,
    double* __restrict__ box_sum,
    int*    __restrict__ pos_cnt)
{
    const int tid   = threadIdx.x;
    const int la    = tid / 20;       // local anchor 0..15
    const int chunk = tid % 20;       // float4 chunk of classes
    const int g = blockIdx.x * 16 + la;       // global (i,a) flat index
    const int i = blockIdx.x >> 12;           // 4096 blocks per batch
    const int a = g & (AB - 1);

    float mi  = max_iou[g];
    bool pos  = (mi >= 0.5f);
    bool tgt  = pos || (mi < 0.4f);   // target_w != 0

    float cls_acc = 0.f;
    float box_acc = 0.f;
    int   posc    = 0;

    if (tgt) {
        const float4* yp = (const float4*)(y_pred + ((long long)g) * CB);
        float4 l4 = yp[chunk];
        float y0 = 0.f, y1 = 0.f, y2 = 0.f, y3 = 0.f;
        int t = 0;
        if (pos) {
            t = assigned[g];
            float4 yv = ((const float4*)(y_true + (size_t)(i * TB + t) * CB))[chunk];
            y0 = yv.x; y1 = yv.y; y2 = yv.z; y3 = yv.w;
        }
        cls_acc = focal_bce(y0, l4.x) + focal_bce(y1, l4.y) +
                  focal_bce(y2, l4.z) + focal_bce(y3, l4.w);

        if (pos && chunk == 0) {
            posc = 1;
            float4 b  = ((const float4*)bbox_true)[i * TB + t];
            float4 an = ((const float4*)anchors)[a];
            float wa = fmaxf(an.z - an.x, EPSF), ha = fmaxf(an.w - an.y, EPSF);
            float cxa = an.x + 0.5f * wa,  cya = an.y + 0.5f * ha;
            float wt = fmaxf(b.z - b.x, EPSF), ht = fmaxf(b.w - b.y, EPSF);
            float cxt = b.x + 0.5f * (b.z - b.x), cyt = b.y + 0.5f * (b.w - b.y);
            float d0 = (cxt - cxa) / wa, d1 = (cyt - cya) / ha;
            float d2 = logf(wt / wa),    d3 = logf(ht / ha);
            float4 bp = ((const float4*)bbox_pred)[g];
            box_acc = smooth_l1(d0 - bp.x) + smooth_l1(d1 - bp.y) +
                      smooth_l1(d2 - bp.z) + smooth_l1(d3 - bp.w);
        }
    }

    // wave (64-lane) shuffle reduction, then cross-wave via shared
    for (int off = 32; off > 0; off >>= 1) {
        cls_acc += __shfl_down(cls_acc, off);
        box_acc += __shfl_down(box_acc, off);
        posc    += __shfl_down(posc, off);
    }
    __shared__ float s_cls[5], s_box[5];
    __shared__ int   s_pc[5];
    int wave = tid >> 6, lane = tid & 63;
    if (lane == 0) { s_cls[wave] = cls_acc; s_box[wave] = box_acc; s_pc[wave] = posc; }
    __syncthreads();
    if (tid == 0) {
        float c = s_cls[0] + s_cls[1] + s_cls[2] + s_cls[3] + s_cls[4];
        float b = s_box[0] + s_box[1] + s_box[2] + s_box[3] + s_box[4];
        int   p = s_pc[0] + s_pc[1] + s_pc[2] + s_pc[3] + s_pc[4];
        atomicAdd(cls_sum, (double)c);
        if (b != 0.f) atomicAdd(box_sum, (double)b);
        if (p)        atomicAdd(&pos_cnt[i], p);
    }
}

// ---------------- kernel D: finalize ----------------
__global__ void finalize_kernel(const double* __restrict__ cls_sum,
                                const double* __restrict__ box_sum,
                                const int* __restrict__ pos_cnt,
                                float* __restrict__ out)
{
    if (threadIdx.x == 0 && blockIdx.x == 0) {
        float avg = 0.f;
        for (int i = 0; i < NB; ++i) avg += fmaxf((float)pos_cnt[i], 1.0f);
        float c = (float)(*cls_sum / (double)avg);
        float b = (float)(*box_sum / (double)avg);
        if (isnan(c) || isinf(c)) c = 0.f;
        if (isnan(b) || isinf(b)) b = 0.f;
        out[0] = c;
        out[1] = b;
    }
}

extern "C" void kernel_launch(void* const* d_in, const int* in_sizes, int n_in,
                              void* d_out, int out_size, void* d_ws, size_t ws_size,
                              hipStream_t stream) {
    const float* y_true    = (const float*)d_in[0];
    const float* bbox_true = (const float*)d_in[1];
    const float* y_pred    = (const float*)d_in[2];
    const float* bbox_pred = (const float*)d_in[3];
    const float* anchors   = (const float*)d_in[4];
    float* out = (float*)d_out;

    char* ws = (char*)d_ws;
    double* cls_sum = (double*)ws;
    double* box_sum = (double*)(ws + 8);
    int*    pos_cnt = (int*)(ws + 16);
    unsigned long long* gt_key = (unsigned long long*)(ws + WS_GTKEY_OFF);
    float*  max_iou  = (float*)(ws + WS_MAXIOU_OFF);
    int*    assigned = (int*)(ws + WS_ASSIGN_OFF);

    // zero accumulators + gt keys (ws is poisoned 0xAA before every launch)
    hipMemsetAsync(ws, 0, WS_HDR_BYTES, stream);

    assign_kernel<<<NB * AB / 256, 256, 0, stream>>>(
        bbox_true, anchors, max_iou, assigned, gt_key);

    lq_kernel<<<1, 64, 0, stream>>>(gt_key, max_iou, assigned);

    loss_kernel<<<NB * AB / 16, 320, 0, stream>>>(
        y_true, bbox_true, y_pred, bbox_pred, anchors,
        max_iou, assigned, cls_sum, box_sum, pos_cnt);

    finalize_kernel<<<1, 64, 0, stream>>>(cls_sum, box_sum, pos_cnt, out);
}

// Round 2
// 296.516 us; speedup vs baseline: 2.5500x; 2.5500x over previous
//
#include <hip/hip_runtime.h>
#include <hip/hip_bf16.h>
#include <math.h>

// Problem constants (from reference): N=8, T=64, A=65536, C=80
#define NB 8
#define TB 64
#define AB 65536
#define CB 80
#define EPSF 1e-6f

#define LOSS_BLOCKS 2048   // 256 per batch
#define LOSS_ITERS  16     // 16 anchors/block/iter * 256 blocks * 16 iters = 65536

// ---------------- workspace layout ----------------
// [0, 4096)                u64   gt_key[N*T]            (must be zeroed)
// [4096, 4096+2MB)         int   code[N*A]              pos->t, neg->-1, ignore->-2
// [+0, +8KB)               float partial_cls[2048]
// [+8KB, +16KB)            float partial_box[2048]
// [+16KB, +24KB)           int   partial_pos[2048]
#define WS_CODE_OFF   4096
#define WS_PCLS_OFF   (4096 + NB*AB*4)
#define WS_PBOX_OFF   (WS_PCLS_OFF + LOSS_BLOCKS*4)
#define WS_PPOS_OFF   (WS_PBOX_OFF + LOSS_BLOCKS*4)

// ---------------- kernel A: anchor<->gt assignment ----------------
// grid: N*A/256 blocks of 256 threads; block = 256 consecutive anchors of one batch
__global__ __launch_bounds__(256) void assign_kernel(
    const float* __restrict__ bbox_true,     // (N,T,4)
    const float* __restrict__ anchors,       // (A,4)
    int*   __restrict__ code,                // (N,A)
    unsigned long long* __restrict__ gt_key) // (N,T)
{
    __shared__ float4 s_box[TB];
    __shared__ float  s_a1[TB];   // gt area, or -1 if invalid
    __shared__ unsigned long long s_key[TB];

    const int blk   = blockIdx.x;
    const int i     = blk >> 8;            // 256 blocks per batch
    const int abase = (blk & 255) << 8;
    const int tid   = threadIdx.x;

    if (tid < TB) {
        float4 b = ((const float4*)bbox_true)[i * TB + tid];
        bool valid = (b.x > 0.f) || (b.y > 0.f) || (b.z > 0.f) || (b.w > 0.f);
        float a1 = fmaxf(b.z - b.x, 0.f) * fmaxf(b.w - b.y, 0.f);
        s_box[tid] = b;
        s_a1[tid]  = valid ? a1 : -1.0f;
        s_key[tid] = 0ull;
    }
    __syncthreads();

    const int a = abase + tid;
    const float4 an = ((const float4*)anchors)[a];
    const float a2 = fmaxf(an.z - an.x, 0.f) * fmaxf(an.w - an.y, 0.f);

    float best = -1.0f;
    int bestt = 0;
    #pragma unroll 8
    for (int t = 0; t < TB; ++t) {
        float a1 = s_a1[t];
        float iou = -1.0f;
        if (a1 >= 0.f) {
            float4 b = s_box[t];
            float lx = fmaxf(b.x, an.x), ly = fmaxf(b.y, an.y);
            float rx = fminf(b.z, an.z), ry = fminf(b.w, an.w);
            float w = fmaxf(rx - lx, 0.f), h = fmaxf(ry - ly, 0.f);
            float inter = w * h;
            float uni = a1 + a2 - inter;
            iou = inter / fmaxf(uni, 1e-10f);
            if (iou > 0.f) {
                // higher iou wins; tie -> smaller anchor index (matches jnp.argmax)
                unsigned long long key =
                    ((unsigned long long)__float_as_uint(iou) << 32) |
                    (unsigned long long)((unsigned)a ^ 0xFFFFFFFFu);
                if (key > s_key[t])  // racy hint; atomic is authoritative
                    atomicMax(&s_key[t], key);
            }
        }
        if (iou > best) { best = iou; bestt = t; }  // strict > => first-index wins
    }
    bool pos = best >= 0.5f;
    bool neg = best < 0.4f;   // includes best==-1 (no valid gt)
    code[i * AB + a] = pos ? bestt : (neg ? -1 : -2);

    __syncthreads();
    if (tid < TB) {
        unsigned long long k = s_key[tid];
        if (k) atomicMax(&gt_key[i * TB + tid], k);
    }
}

// ---------------- kernel B: low-quality match override ----------------
// 512 threads = 8 batches x 64 gts. last-gt-wins for duplicate best anchors
// (matches the sequential scatter semantics the numpy reference uses).
__global__ void lq_kernel(const unsigned long long* __restrict__ gt_key,
                          int* __restrict__ code)
{
    __shared__ unsigned long long sk[NB * TB];
    const int tid = threadIdx.x;
    sk[tid] = gt_key[tid];
    __syncthreads();
    const int i = tid >> 6, t = tid & 63;
    unsigned long long k = sk[tid];
    if (k) {
        unsigned a = (unsigned)(k & 0xFFFFFFFFull) ^ 0xFFFFFFFFu;
        bool win = true;
        for (int t2 = t + 1; t2 < TB; ++t2) {
            unsigned long long k2 = sk[(i << 6) | t2];
            if (k2 && (((unsigned)(k2 & 0xFFFFFFFFull) ^ 0xFFFFFFFFu) == a))
                win = false;  // a later gt claims the same anchor
        }
        if (win) code[i * AB + (int)a] = t;   // force positive, assigned = t
    }
}

// ---------------- fast focal / smooth-l1 ----------------
// threshold is 35.84 on O(1e3) outputs -> native transcendentals are plenty.
__device__ __forceinline__ float focal1(bool ypos, float l) {
    float q  = __expf(-fabsf(l));                    // v_exp_f32
    float r  = __builtin_amdgcn_rcpf(1.f + q);       // v_rcp_f32
    float lg = __logf(r);                            // v_log_f32; -lg = log1p(q)
    float ce = fmaxf(l, 0.f) - (ypos ? l : 0.f) - lg;
    float p  = (l >= 0.f) ? r : 1.f - r;             // sigmoid(l)
    float pt = ypos ? p : 1.f - p;
    float at = ypos ? 0.25f : 0.75f;
    float om = 1.f - pt;
    return at * om * om * ce;
}
__device__ __forceinline__ float smooth_l1(float x) {
    float d = fabsf(x);
    return d < (1.f / 9.f) ? 4.5f * d * d : d - (0.5f / 9.f);
}

// ---------------- kernel C: loss accumulation ----------------
// 320 threads = 16 anchors x 20 float4-chunks of 80 classes.
// 2048 blocks (256/batch), 16 grid-stride iterations; per-block partials, NO atomics.
__global__ __launch_bounds__(320) void loss_kernel(
    const float* __restrict__ y_true,     // (N,T,C)
    const float* __restrict__ bbox_true,  // (N,T,4)
    const float* __restrict__ y_pred,     // (N,A,C)
    const float* __restrict__ bbox_pred,  // (N,A,4)
    const float* __restrict__ anchors,    // (A,4)
    const int*   __restrict__ code,       // (N,A)
    float* __restrict__ partial_cls,
    float* __restrict__ partial_box,
    int*   __restrict__ partial_pos)
{
    const int tid   = threadIdx.x;
    const int la    = tid / 20;       // local anchor 0..15
    const int chunk = tid % 20;       // float4 chunk of classes
    const int b   = blockIdx.x;
    const int i   = b >> 8;
    const int sub = b & 255;

    const float4* yp4 = (const float4*)y_pred;
    const float4* yt4 = (const float4*)y_true;

    float cls_acc = 0.f, box_acc = 0.f;
    int posc = 0;

    #pragma unroll 2
    for (int it = 0; it < LOSS_ITERS; ++it) {
        const int a = sub * 16 + la + it * (256 * 16);
        const int g = i * AB + a;
        const int cv = code[g];
        float4 l4 = yp4[g * 20 + chunk];    // hoisted: unconditional, coalesced
        if (cv != -2) {
            bool pos = cv >= 0;
            float y0 = 0.f, y1 = 0.f, y2 = 0.f, y3 = 0.f;
            if (pos) {
                float4 yv = yt4[(i * TB + cv) * 20 + chunk];
                y0 = yv.x; y1 = yv.y; y2 = yv.z; y3 = yv.w;
            }
            cls_acc += focal1(y0 != 0.f, l4.x) + focal1(y1 != 0.f, l4.y) +
                       focal1(y2 != 0.f, l4.z) + focal1(y3 != 0.f, l4.w);
            if (pos && chunk == 0) {
                posc += 1;
                float4 bt = ((const float4*)bbox_true)[i * TB + cv];
                float4 an = ((const float4*)anchors)[a];
                float wa = fmaxf(an.z - an.x, EPSF), ha = fmaxf(an.w - an.y, EPSF);
                float cxa = an.x + 0.5f * wa,  cya = an.y + 0.5f * ha;
                float wt = fmaxf(bt.z - bt.x, EPSF), ht = fmaxf(bt.w - bt.y, EPSF);
                float cxt = bt.x + 0.5f * (bt.z - bt.x), cyt = bt.y + 0.5f * (bt.w - bt.y);
                float d0 = (cxt - cxa) / wa, d1 = (cyt - cya) / ha;
                float d2 = __logf(wt / wa),  d3 = __logf(ht / ha);
                float4 bp = ((const float4*)bbox_pred)[g];
                box_acc += smooth_l1(d0 - bp.x) + smooth_l1(d1 - bp.y) +
                           smooth_l1(d2 - bp.z) + smooth_l1(d3 - bp.w);
            }
        }
    }

    // 64-lane shuffle reduce, then cross-wave via shared, one store per block
    for (int off = 32; off > 0; off >>= 1) {
        cls_acc += __shfl_down(cls_acc, off);
        box_acc += __shfl_down(box_acc, off);
        posc    += __shfl_down(posc, off);
    }
    __shared__ float s_cls[5], s_box[5];
    __shared__ int   s_pc[5];
    int wave = tid >> 6, lane = tid & 63;
    if (lane == 0) { s_cls[wave] = cls_acc; s_box[wave] = box_acc; s_pc[wave] = posc; }
    __syncthreads();
    if (tid == 0) {
        partial_cls[b] = s_cls[0] + s_cls[1] + s_cls[2] + s_cls[3] + s_cls[4];
        partial_box[b] = s_box[0] + s_box[1] + s_box[2] + s_box[3] + s_box[4];
        partial_pos[b] = s_pc[0] + s_pc[1] + s_pc[2] + s_pc[3] + s_pc[4];
    }
}

// ---------------- kernel D: final reduce + divide + sanitize ----------------
// one block, 256 threads. 2048 partials; pos counts are per-batch (256 blocks/batch).
__global__ __launch_bounds__(256) void reduce_kernel(
    const float* __restrict__ partial_cls,
    const float* __restrict__ partial_box,
    const int*   __restrict__ partial_pos,
    float* __restrict__ out)
{
    const int tid = threadIdx.x;
    const int wave = tid >> 6, lane = tid & 63;
    __shared__ double sc[4], sb[4];
    __shared__ int    si[4];
    __shared__ float  s_avg;

    double c = 0.0, bx = 0.0;
    #pragma unroll
    for (int j = 0; j < LOSS_BLOCKS / 256; ++j) {
        c  += (double)partial_cls[tid + j * 256];
        bx += (double)partial_box[tid + j * 256];
    }

    // per-batch positive counts -> avg_factor
    float avg = 0.f;
    for (int bb = 0; bb < NB; ++bb) {
        int p = partial_pos[bb * 256 + tid];
        for (int off = 32; off > 0; off >>= 1) p += __shfl_down(p, off);
        if (lane == 0) si[wave] = p;
        __syncthreads();
        if (tid == 0) {
            int tot = si[0] + si[1] + si[2] + si[3];
            avg += fmaxf((float)tot, 1.0f);
        }
        __syncthreads();
    }
    if (tid == 0) s_avg = avg;

    for (int off = 32; off > 0; off >>= 1) {
        c  += __shfl_down(c, off);
        bx += __shfl_down(bx, off);
    }
    if (lane == 0) { sc[wave] = c; sb[wave] = bx; }
    __syncthreads();
    if (tid == 0) {
        double ct = sc[0] + sc[1] + sc[2] + sc[3];
        double bt = sb[0] + sb[1] + sb[2] + sb[3];
        float cf = (float)(ct / (double)s_avg);
        float bf = (float)(bt / (double)s_avg);
        if (isnan(cf) || isinf(cf)) cf = 0.f;
        if (isnan(bf) || isinf(bf)) bf = 0.f;
        out[0] = cf;
        out[1] = bf;
    }
}

extern "C" void kernel_launch(void* const* d_in, const int* in_sizes, int n_in,
                              void* d_out, int out_size, void* d_ws, size_t ws_size,
                              hipStream_t stream) {
    const float* y_true    = (const float*)d_in[0];
    const float* bbox_true = (const float*)d_in[1];
    const float* y_pred    = (const float*)d_in[2];
    const float* bbox_pred = (const float*)d_in[3];
    const float* anchors   = (const float*)d_in[4];
    float* out = (float*)d_out;

    char* ws = (char*)d_ws;
    unsigned long long* gt_key = (unsigned long long*)ws;
    int*   code        = (int*)(ws + WS_CODE_OFF);
    float* partial_cls = (float*)(ws + WS_PCLS_OFF);
    float* partial_box = (float*)(ws + WS_PBOX_OFF);
    int*   partial_pos = (int*)(ws + WS_PPOS_OFF);

    // zero only gt_key (atomicMax baseline); partials are fully overwritten
    hipMemsetAsync(ws, 0, NB * TB * sizeof(unsigned long long), stream);

    assign_kernel<<<NB * AB / 256, 256, 0, stream>>>(bbox_true, anchors, code, gt_key);
    lq_kernel<<<1, NB * TB, 0, stream>>>(gt_key, code);
    loss_kernel<<<LOSS_BLOCKS, 320, 0, stream>>>(
        y_true, bbox_true, y_pred, bbox_pred, anchors, code,
        partial_cls, partial_box, partial_pos);
    reduce_kernel<<<1, 256, 0, stream>>>(partial_cls, partial_box, partial_pos, out);
}